// Round 17
// baseline (817.576 us; speedup 1.0000x reference)
//
#include <hip/hip_runtime.h>
#include <hip/hip_bf16.h>
#include <math.h>

typedef unsigned short u16;
typedef __bf16 bf16x8 __attribute__((ext_vector_type(8)));
typedef float f32x4 __attribute__((ext_vector_type(4)));

// ---------------------------------------------------------------------------
// Hetero-GAT forward, bf16 hi/lo split MFMA.
//  - agg<->GEMM commute for layers 1-2; per-edge softmax weights precomputed.
//  - r13-proven BM=64 GEMM structure (untouched k-loop).
//  - NEW: es/ed attention dots fused into GEMM epilogues via LDS-tile reuse
//    (deletes es_ed2 dispatches + x re-reads); fc1/penalty fused into the
//    layer-3 aggregation tail (deletes fc1_halves + final x materialization).
// ---------------------------------------------------------------------------

__device__ inline float bfbits2f(u16 u) {
    unsigned int v = ((unsigned int)u) << 16;
    float f;
    __builtin_memcpy(&f, &v, 4);
    return f;
}
__device__ inline u16 f2bf(float x) {
    __hip_bfloat16 h = __float2bfloat16(x);
    u16 u;
    __builtin_memcpy(&u, &h, 2);
    return u;
}

#define GLD16(gp, lp) __builtin_amdgcn_global_load_lds( \
    (__attribute__((address_space(1))) void*)(gp),      \
    (__attribute__((address_space(3))) void*)(lp), 16, 0, 0)

// ---------------- shared structs -------------------------------------------
struct SplitJobs {
    const float* src[8];
    u16* dst[8];
    int K[8];
    int Kp[8];
    int J[8];
    int offs[9];
};

struct UParams {
    const float* Ws[6];
    const float* Wd[6];
    const float* as_[6];
    const float* ad_[6];
    int C[6];
};

struct GemmPairF {
    const float* A0; const u16* B0; const float* bias0;
    const float* emb0; const int* ids0; float* C0; int K0; int Kp0;
    const float* A1; const u16* B1; const float* bias1;
    const float* emb1; const int* ids1; float* C1; int K1; int Kp1;
};

// ---------------- es/ed epilogue over an LDS bf16 tile ---------------------
// tile: 64 rows x 128 cols, stride 132 u16. is_xl selects the dst mapping.
__device__ __forceinline__ void esed_epilogue(
    const u16* tile, int rowbase, int N, int is_xl,
    const float* __restrict__ U1, const float* __restrict__ U2,
    float* __restrict__ es1, float* __restrict__ ed1,
    float* __restrict__ es2, float* __restrict__ ed2, int tid)
{
#pragma unroll
    for (int q = 0; q < 2; ++q) {
        int d = tid * 2 + q;
        int row = d >> 3, j = d & 7;
        int gr = rowbase + row;
        if (gr >= N) continue;
        const float* U; float* dst; int ucol;
        if (!is_xl) {
            if (j < 4) { U = U1; ucol = j;     dst = &es1[gr * 4 + j]; }
            else       { U = U2; ucol = j;     dst = &ed2[gr * 4 + j - 4]; }
        } else {
            if (j < 4) { U = U1; ucol = j + 4; dst = &ed1[gr * 4 + j]; }
            else       { U = U2; ucol = j - 4; dst = &es2[gr * 4 + j - 4]; }
        }
        float s = 0.f;
        const int ph = (tid & 3) << 5;
        for (int kk = 0; kk < 128; ++kk) {
            int k = (kk + ph) & 127;
            s = fmaf(bfbits2f(tile[row * 132 + k]), U[k * 8 + ucol], s);
        }
        *dst = s;
    }
}

// ---------------- GEMM body (r13 k-loop) + optional es/ed epilogue ---------
template<bool BIAS_EMB, bool DO_ESED>
__device__ __forceinline__ void gemm_f32a_body(
    const float* __restrict__ A, const u16* __restrict__ Bhi,
    const float* __restrict__ bias, const float* __restrict__ emb,
    const int* __restrict__ ids, float* __restrict__ C,
    int K, int Kp, int N, int is_xl,
    const float* __restrict__ U1, const float* __restrict__ U2,
    float* __restrict__ es1, float* __restrict__ ed1,
    float* __restrict__ es2, float* __restrict__ ed2)
{
    __shared__ __align__(16) u16 smem[12288];   // 24KB: staging, then tile
    u16* sAh = smem;
    u16* sAl = smem + 2048;
    u16* sBh = smem + 4096;
    u16* sBl = smem + 8192;
    const int tid = threadIdx.x;
    const int lane = tid & 63;
    const int wid = tid >> 6;
    const int rowbase = blockIdx.x * 64;

    const u16* Blo = Bhi + (size_t)128 * Kp;
    const int nk = Kp / 32;

    const int ar = tid >> 2;
    const int ac = tid & 3;
    const int aswz = (ar >> 1) & 3;
    int gra = rowbase + ar; if (gra >= N) gra = N - 1;
    const size_t aoffA = (size_t)gra * K + (size_t)(ac * 8);
    const int asto = ar * 32 + ((ac ^ aswz) << 3);

    const int brow = tid >> 2;
    const int bkc = tid & 3;
    const int bswz = (brow >> 1) & 3;
    const size_t boff0 = (size_t)brow * Kp + (size_t)((bkc ^ bswz) * 8);
    const size_t boff1 = (size_t)(64 + brow) * Kp + (size_t)((bkc ^ bswz) * 8);

    const int kgs = ((lane >> 4) ^ ((lane >> 1) & 3)) * 8;
    const int arow_rd = lane & 15;
    const int brow_rd = wid * 32 + (lane & 15);

    f32x4 acc[4][2] = {};

    for (int ks = 0; ks < nk; ++ks) {
        const int k0 = ks * 32;
        GLD16(Bhi + boff0 + k0, &sBh[(size_t)tid * 8]);
        GLD16(Bhi + boff1 + k0, &sBh[(size_t)(tid + 256) * 8]);
        GLD16(Blo + boff0 + k0, &sBl[(size_t)tid * 8]);
        GLD16(Blo + boff1 + k0, &sBl[(size_t)(tid + 256) * 8]);
        float4 av0 = make_float4(0.f, 0.f, 0.f, 0.f);
        float4 av1 = make_float4(0.f, 0.f, 0.f, 0.f);
        const int kc = k0 + ac * 8;
        if (kc < K)     av0 = *reinterpret_cast<const float4*>(&A[aoffA + k0]);
        if (kc + 4 < K) av1 = *reinterpret_cast<const float4*>(&A[aoffA + k0 + 4]);
        float vv[8] = {av0.x, av0.y, av0.z, av0.w, av1.x, av1.y, av1.z, av1.w};
        u16 h[8], l[8];
#pragma unroll
        for (int j = 0; j < 8; ++j) {
            u16 hb = f2bf(vv[j]);
            h[j] = hb;
            l[j] = f2bf(vv[j] - bfbits2f(hb));
        }
        uint4 hp, lp;
        hp.x = (unsigned)h[0] | ((unsigned)h[1] << 16);
        hp.y = (unsigned)h[2] | ((unsigned)h[3] << 16);
        hp.z = (unsigned)h[4] | ((unsigned)h[5] << 16);
        hp.w = (unsigned)h[6] | ((unsigned)h[7] << 16);
        lp.x = (unsigned)l[0] | ((unsigned)l[1] << 16);
        lp.y = (unsigned)l[2] | ((unsigned)l[3] << 16);
        lp.z = (unsigned)l[4] | ((unsigned)l[5] << 16);
        lp.w = (unsigned)l[6] | ((unsigned)l[7] << 16);
        *reinterpret_cast<uint4*>(&sAh[asto]) = hp;
        *reinterpret_cast<uint4*>(&sAl[asto]) = lp;
        __syncthreads();
        bf16x8 bh[2], bl[2];
#pragma unroll
        for (int n = 0; n < 2; ++n) {
            bh[n] = *reinterpret_cast<const bf16x8*>(&sBh[(brow_rd + n * 16) * 32 + kgs]);
            bl[n] = *reinterpret_cast<const bf16x8*>(&sBl[(brow_rd + n * 16) * 32 + kgs]);
        }
#pragma unroll
        for (int m = 0; m < 4; ++m) {
            bf16x8 ah = *reinterpret_cast<const bf16x8*>(&sAh[(arow_rd + m * 16) * 32 + kgs]);
            bf16x8 al = *reinterpret_cast<const bf16x8*>(&sAl[(arow_rd + m * 16) * 32 + kgs]);
#pragma unroll
            for (int n = 0; n < 2; ++n) {
                acc[m][n] = __builtin_amdgcn_mfma_f32_16x16x32_bf16(ah, bh[n], acc[m][n], 0, 0, 0);
                acc[m][n] = __builtin_amdgcn_mfma_f32_16x16x32_bf16(ah, bl[n], acc[m][n], 0, 0, 0);
                acc[m][n] = __builtin_amdgcn_mfma_f32_16x16x32_bf16(al, bh[n], acc[m][n], 0, 0, 0);
            }
        }
        __syncthreads();
    }

#pragma unroll
    for (int m = 0; m < 4; ++m) {
        int rl = m * 16 + ((lane >> 4) << 2);
#pragma unroll
        for (int i = 0; i < 4; ++i) {
            int r = rowbase + rl + i;
            if (r >= N) continue;
            const float* ep = nullptr;
            if (BIAS_EMB) ep = emb + (size_t)ids[r] * 128;
#pragma unroll
            for (int n = 0; n < 2; ++n) {
                int col = wid * 32 + n * 16 + (lane & 15);
                float v = acc[m][n][i];
                if (BIAS_EMB) v += bias[col] + ep[col];
                C[(size_t)r * 128 + col] = v;
                if (DO_ESED) smem[(rl + i) * 132 + col] = f2bf(v);
            }
        }
    }

    if (DO_ESED) {
        __syncthreads();
        esed_epilogue(smem, rowbase, N, is_xl, U1, U2, es1, ed1, es2, ed2, tid);
    }
}

// ---------------- fused: weight splits || compute_U ------------------------
__global__ __launch_bounds__(256) void k_split_U(SplitJobs SJ, UParams P,
                                                 float* __restrict__ U)
{
    if (blockIdx.y == 0) {
        int t = blockIdx.x * 256 + threadIdx.x;
        if (t >= SJ.offs[8]) return;
        int j = 0;
#pragma unroll
        for (int q = 1; q < 8; ++q) if (t >= SJ.offs[q]) j = q;
        int e = t - SJ.offs[j];
        int Kp = SJ.Kp[j], K = SJ.K[j], J = SJ.J[j];
        const float* B = SJ.src[j];
        u16* hi = SJ.dst[j];
        int col = e / Kp, k = e - col * Kp;
        float v = (k < K) ? B[(size_t)k * J + col] : 0.f;
        u16 hb = f2bf(v);
        hi[e] = hb;
        hi[(size_t)J * Kp + e] = f2bf(v - bfbits2f(hb));
        return;
    }
    int w = (blockIdx.x * 256 + threadIdx.x) >> 6;
    if (w >= 6144) return;
    int lane = threadIdx.x & 63;
    int g = w >> 10;
    int o = w & 1023;
    int k = o >> 3, j = o & 7, h = j & 3;
    int C = P.C[g];
    int HC = 4 * C;
    const float* W = (j < 4) ? P.Ws[g] : P.Wd[g];
    const float* a = (j < 4) ? P.as_[g] : P.ad_[g];
    float s = 0.f;
    for (int c = lane; c < C; c += 64)
        s = fmaf(W[k * HC + h * C + c], a[h * C + c], s);
#pragma unroll
    for (int off = 32; off >= 1; off >>= 1) s += __shfl_xor(s, off, 64);
    if (lane == 0) U[g * 1024 + o] = s;
}

// ---------------- fused: input GEMM pair (+es/ed) || degree count ----------
__global__ __launch_bounds__(256) void k_gemm_input_deg(
    GemmPairF P, int N, int n64,
    const int* __restrict__ s, const int* __restrict__ t,
    int* __restrict__ deg_t, int* __restrict__ deg_s, int E,
    const float* __restrict__ U1, const float* __restrict__ U2,
    float* __restrict__ es1, float* __restrict__ ed1,
    float* __restrict__ es2, float* __restrict__ ed2)
{
    if (blockIdx.y < 2) {
        if ((int)blockIdx.x >= n64) return;
        if (blockIdx.y == 0)
            gemm_f32a_body<true, true>(P.A0, P.B0, P.bias0, P.emb0, P.ids0, P.C0,
                                       P.K0, P.Kp0, N, 0, U1, U2, es1, ed1, es2, ed2);
        else
            gemm_f32a_body<true, true>(P.A1, P.B1, P.bias1, P.emb1, P.ids1, P.C1,
                                       P.K1, P.Kp1, N, 1, U1, U2, es1, ed1, es2, ed2);
        return;
    }
    int i = blockIdx.x * 256 + threadIdx.x;
    if (i >= E) return;
    atomicAdd(&deg_t[t[i]], 1);
    atomicAdd(&deg_s[s[i]], 1);
}

// ---------------- layer-3 GEMM pair (no es/ed) -----------------------------
__global__ __launch_bounds__(256) void k_gemm_l3(GemmPairF P, int N)
{
    if (blockIdx.y == 0)
        gemm_f32a_body<false, false>(P.A0, P.B0, P.bias0, P.emb0, P.ids0, P.C0,
                                     P.K0, P.Kp0, N, 0,
                                     nullptr, nullptr, nullptr, nullptr, nullptr, nullptr);
    else
        gemm_f32a_body<false, false>(P.A1, P.B1, P.bias1, P.emb1, P.ids1, P.C1,
                                     P.K1, P.Kp1, N, 1,
                                     nullptr, nullptr, nullptr, nullptr, nullptr, nullptr);
}

// ---------------- scans ----------------------------------------------------
__global__ void scan_partial(const int* dA, const int* dB, int* eA, int* eB,
                             int* bsA, int* bsB, int N)
{
    __shared__ int lds[256];
    const int* deg = blockIdx.y ? dB : dA;
    int* ex = blockIdx.y ? eB : eA;
    int* bs = blockIdx.y ? bsB : bsA;
    int i = blockIdx.x * 256 + threadIdx.x;
    int v = (i < N) ? deg[i] : 0;
    int x = v;
    lds[threadIdx.x] = x;
    __syncthreads();
    for (int off = 1; off < 256; off <<= 1) {
        int tv = (threadIdx.x >= off) ? lds[threadIdx.x - off] : 0;
        __syncthreads();
        x += tv;
        lds[threadIdx.x] = x;
        __syncthreads();
    }
    if (i < N) ex[i] = x - v;
    if (threadIdx.x == 255) bs[blockIdx.x] = x;
}

__global__ void scan_bsums(int* bsA, int* bsB, int* boA, int* boB, int nb)
{
    __shared__ int lds[256];
    int* bs = blockIdx.y ? bsB : bsA;
    int* bo = blockIdx.y ? boB : boA;
    int v = (threadIdx.x < nb) ? bs[threadIdx.x] : 0;
    int x = v;
    lds[threadIdx.x] = x;
    __syncthreads();
    for (int off = 1; off < 256; off <<= 1) {
        int tv = (threadIdx.x >= off) ? lds[threadIdx.x - off] : 0;
        __syncthreads();
        x += tv;
        lds[threadIdx.x] = x;
        __syncthreads();
    }
    if (threadIdx.x < nb) bo[threadIdx.x] = x - v;
    if (threadIdx.x == 255) bo[nb] = x;
}

__global__ void scan_add(int* eA, int* eB, const int* boA, const int* boB, int N, int nb)
{
    int* ex = blockIdx.y ? eB : eA;
    const int* bo = blockIdx.y ? boB : boA;
    int i = blockIdx.x * 256 + threadIdx.x;
    if (i < N) ex[i] += bo[i >> 8];
    if (i == 0) ex[N] = bo[nb];
}

__global__ void fill_kernel(const int* __restrict__ s, const int* __restrict__ t,
                            const int* __restrict__ rpt_t, const int* __restrict__ rpt_s,
                            int* __restrict__ cur_t, int* __restrict__ cur_s,
                            int* __restrict__ col_t, int* __restrict__ col_s,
                            int* __restrict__ row_t, int* __restrict__ row_s, int E)
{
    int i = blockIdx.x * blockDim.x + threadIdx.x;
    if (i >= E) return;
    int sv = s[i], tv = t[i];
    int p = atomicAdd(&cur_t[tv], 1);
    int pos = rpt_t[tv] + p;
    col_t[pos] = sv; row_t[pos] = tv;
    p = atomicAdd(&cur_s[sv], 1);
    pos = rpt_s[sv] + p;
    col_s[pos] = tv; row_s[pos] = sv;
}

// ---------------- per-edge softmax weights (no-max, CSR order) ------------
__global__ __launch_bounds__(256) void edge_w_kernel(
    const int* __restrict__ col_t, const int* __restrict__ row_t,
    const int* __restrict__ col_s, const int* __restrict__ row_s,
    const float* __restrict__ es1, const float* __restrict__ ed1,
    const float* __restrict__ es2, const float* __restrict__ ed2,
    float* __restrict__ w_t, float* __restrict__ w_s, int E)
{
    int i = blockIdx.x * 256 + threadIdx.x;
    if (i >= E) return;
    const int* col; const int* row; const float* es; const float* ed; float* w;
    if (blockIdx.y == 0) { col = col_t; row = row_t; es = es1; ed = ed1; w = w_t; }
    else                 { col = col_s; row = row_s; es = es2; ed = ed2; w = w_s; }
    int sn = col[i], rn = row[i];
    float4 a = *reinterpret_cast<const float4*>(&es[(size_t)sn * 4]);
    float4 b = *reinterpret_cast<const float4*>(&ed[(size_t)rn * 4]);
    float v0 = a.x + b.x; v0 = v0 > 0.f ? v0 : 0.2f * v0;
    float v1 = a.y + b.y; v1 = v1 > 0.f ? v1 : 0.2f * v1;
    float v2 = a.z + b.z; v2 = v2 > 0.f ? v2 : 0.2f * v2;
    float v3 = a.w + b.w; v3 = v3 > 0.f ? v3 : 0.2f * v3;
    float4 o;
    o.x = __expf(v0); o.y = __expf(v1); o.z = __expf(v2); o.w = __expf(v3);
    *reinterpret_cast<float4*>(&w[(size_t)i * 4]) = o;
}

// ---------------- per-head x-aggregation pair (layers 1-2) ----------------
struct AggXPair {
    const int* rpt0; const int* col0; const float* w0; const float* x0; u16* out0;
    const int* rpt1; const int* col1; const float* w1; const float* x1; u16* out1;
};

__global__ __launch_bounds__(256) void agg_x2(AggXPair P, int Ndst)
{
    int n = blockIdx.x * 4 + (threadIdx.x >> 6);
    if (n >= Ndst) return;
    const bool y1 = (blockIdx.y == 1);
    const int* rowptr  = y1 ? P.rpt1 : P.rpt0;
    const int* cols    = y1 ? P.col1 : P.col0;
    const float* wbuf  = y1 ? P.w1 : P.w0;
    const float* xsrc  = y1 ? P.x1 : P.x0;
    u16* aggp          = y1 ? P.out1 : P.out0;

    int lane = threadIdx.x & 63;
    int beg = rowptr[n], end = rowptr[n + 1];

    float den0 = 0.f, den1 = 0.f, den2 = 0.f, den3 = 0.f;
    float2 acc[4] = {};

    for (int i = beg; i < end; ++i) {
        float4 w4 = *reinterpret_cast<const float4*>(&wbuf[(size_t)i * 4]);
        den0 += w4.x; den1 += w4.y; den2 += w4.z; den3 += w4.w;
        int sn = cols[i];
        float2 xv = *reinterpret_cast<const float2*>(&xsrc[(size_t)sn * 128 + 2 * lane]);
        acc[0].x = fmaf(w4.x, xv.x, acc[0].x); acc[0].y = fmaf(w4.x, xv.y, acc[0].y);
        acc[1].x = fmaf(w4.y, xv.x, acc[1].x); acc[1].y = fmaf(w4.y, xv.y, acc[1].y);
        acc[2].x = fmaf(w4.z, xv.x, acc[2].x); acc[2].y = fmaf(w4.z, xv.y, acc[2].y);
        acc[3].x = fmaf(w4.w, xv.x, acc[3].x); acc[3].y = fmaf(w4.w, xv.y, acc[3].y);
    }

    float inv[4] = {1.f / (den0 + 1e-16f), 1.f / (den1 + 1e-16f),
                    1.f / (den2 + 1e-16f), 1.f / (den3 + 1e-16f)};
    u16* lo = aggp + (size_t)Ndst * 512;
    size_t base = (size_t)n * 512 + 2 * lane;
#pragma unroll
    for (int h = 0; h < 4; ++h) {
        float v0 = acc[h].x * inv[h];
        float v1 = acc[h].y * inv[h];
        u16 h0 = f2bf(v0), h1 = f2bf(v1);
        *reinterpret_cast<unsigned*>(&aggp[base + h * 128]) =
            (unsigned)h0 | ((unsigned)h1 << 16);
        u16 l0 = f2bf(v0 - bfbits2f(h0)), l1 = f2bf(v1 - bfbits2f(h1));
        *reinterpret_cast<unsigned*>(&lo[base + h * 128]) =
            (unsigned)l0 | ((unsigned)l1 << 16);
    }
}

// ---------------- head-blocked GEMM pair + relu/mean + es/ed epilogue ------
struct HeadsPair {
    const u16* A0; const u16* B0; const float* bias0; float* C0; int xl0;
    const u16* A1; const u16* B1; const float* bias1; float* C1; int xl1;
    const float* U1n; const float* U2n;
    float* es1; float* ed1; float* es2; float* ed2;
};

__global__ __launch_bounds__(256) void gemm_heads2(HeadsPair P, int N)
{
    __shared__ __align__(16) u16 smem[12288];
    u16* sAh = smem;
    u16* sAl = smem + 2048;
    u16* sBh = smem + 4096;
    u16* sBl = smem + 8192;
    const int tid = threadIdx.x;
    const int lane = tid & 63;
    const int wid = tid >> 6;
    const int rowbase = blockIdx.x * 64;

    const bool y1 = (blockIdx.y == 1);
    const u16* Ahi = y1 ? P.A1 : P.A0;
    const u16* Bhi = y1 ? P.B1 : P.B0;
    const float* bias = y1 ? P.bias1 : P.bias0;
    float* C = y1 ? P.C1 : P.C0;
    const int is_xl = y1 ? P.xl1 : P.xl0;

    const u16* Alo = Ahi + (size_t)N * 512;
    const u16* Blo = Bhi + (size_t)512 * 128;

    const int akc = tid & 3;
    const int arow = tid >> 2;
    const int swz = (arow >> 1) & 3;
    int gr = rowbase + arow; if (gr >= N) gr = N - 1;
    const size_t aoff  = (size_t)gr * 512 + (size_t)((akc ^ swz) * 8);
    const size_t boff0 = (size_t)arow * 128 + (size_t)((akc ^ swz) * 8);
    const size_t boff1 = (size_t)(64 + arow) * 128 + (size_t)((akc ^ swz) * 8);

    const int kgs = ((lane >> 4) ^ ((lane >> 1) & 3)) * 8;
    const int arow_rd = lane & 15;
    const int brow_rd = wid * 32 + (lane & 15);

    f32x4 acc[4][2] = {};
    f32x4 runsum[4][2] = {};

    for (int h = 0; h < 4; ++h) {
        const size_t ha = (size_t)h * 128;
        const size_t hb = (size_t)h * 128 * 128;
#pragma unroll
        for (int ks = 0; ks < 4; ++ks) {
            const int k0 = ks * 32;
            GLD16(Ahi + aoff + ha + k0,  &sAh[(size_t)tid * 8]);
            GLD16(Alo + aoff + ha + k0,  &sAl[(size_t)tid * 8]);
            GLD16(Bhi + boff0 + hb + k0, &sBh[(size_t)tid * 8]);
            GLD16(Bhi + boff1 + hb + k0, &sBh[(size_t)(tid + 256) * 8]);
            GLD16(Blo + boff0 + hb + k0, &sBl[(size_t)tid * 8]);
            GLD16(Blo + boff1 + hb + k0, &sBl[(size_t)(tid + 256) * 8]);
            __syncthreads();
            bf16x8 bh[2], bl[2];
#pragma unroll
            for (int n = 0; n < 2; ++n) {
                bh[n] = *reinterpret_cast<const bf16x8*>(&sBh[(brow_rd + n * 16) * 32 + kgs]);
                bl[n] = *reinterpret_cast<const bf16x8*>(&sBl[(brow_rd + n * 16) * 32 + kgs]);
            }
#pragma unroll
            for (int m = 0; m < 4; ++m) {
                bf16x8 ah = *reinterpret_cast<const bf16x8*>(&sAh[(arow_rd + m * 16) * 32 + kgs]);
                bf16x8 al = *reinterpret_cast<const bf16x8*>(&sAl[(arow_rd + m * 16) * 32 + kgs]);
#pragma unroll
                for (int n = 0; n < 2; ++n) {
                    acc[m][n] = __builtin_amdgcn_mfma_f32_16x16x32_bf16(ah, bh[n], acc[m][n], 0, 0, 0);
                    acc[m][n] = __builtin_amdgcn_mfma_f32_16x16x32_bf16(ah, bl[n], acc[m][n], 0, 0, 0);
                    acc[m][n] = __builtin_amdgcn_mfma_f32_16x16x32_bf16(al, bh[n], acc[m][n], 0, 0, 0);
                }
            }
            __syncthreads();
        }
#pragma unroll
        for (int m = 0; m < 4; ++m)
#pragma unroll
            for (int n = 0; n < 2; ++n) {
                int col = wid * 32 + n * 16 + (lane & 15);
                float b = bias[h * 128 + col];
#pragma unroll
                for (int i = 0; i < 4; ++i) {
                    runsum[m][n][i] += fmaxf(acc[m][n][i] + b, 0.f);
                    acc[m][n][i] = 0.f;
                }
            }
    }

#pragma unroll
    for (int m = 0; m < 4; ++m) {
        int rl = m * 16 + ((lane >> 4) << 2);
#pragma unroll
        for (int i = 0; i < 4; ++i) {
            int r = rowbase + rl + i;
            if (r >= N) continue;
#pragma unroll
            for (int n = 0; n < 2; ++n) {
                int col = wid * 32 + n * 16 + (lane & 15);
                float v = 0.25f * runsum[m][n][i];
                C[(size_t)r * 128 + col] = v;
                smem[(rl + i) * 132 + col] = f2bf(v);
            }
        }
    }

    __syncthreads();
    esed_epilogue(smem, rowbase, N, is_xl, P.U1n, P.U2n,
                  P.es1, P.ed1, P.es2, P.ed2, tid);
}

// ---------------- layer-3 aggregation + fused penalty/fc1 tables -----------
struct Agg128Pair {
    const int* rpt0; const int* col0; const float* w0;
    const float* hs0; const float* bias0;
    const float* pW0; const float* pb0; const float* fcW0; float* tab0;
    const int* rpt1; const int* col1; const float* w1;
    const float* hs1; const float* bias1;
    const float* pW1; const float* pb1; const float* fcW1; float* tab1;
};

__global__ __launch_bounds__(256) void gat_agg128_fc1(Agg128Pair P, int Ndst)
{
    int n = blockIdx.x * 4 + (threadIdx.x >> 6);
    if (n >= Ndst) return;
    const bool y1 = (blockIdx.y == 1);
    const int* rowptr = y1 ? P.rpt1 : P.rpt0;
    const int* cols   = y1 ? P.col1 : P.col0;
    const float* wbuf = y1 ? P.w1 : P.w0;
    const float* hs   = y1 ? P.hs1 : P.hs0;
    const float* bias = y1 ? P.bias1 : P.bias0;
    const float* pW   = y1 ? P.pW1 : P.pW0;
    const float* pb   = y1 ? P.pb1 : P.pb0;
    const float* fcW  = y1 ? P.fcW1 : P.fcW0;
    float* tab        = y1 ? P.tab1 : P.tab0;

    int lane = threadIdx.x & 63;
    int beg = rowptr[n], end = rowptr[n + 1];

    float den0 = 0.f, den1 = 0.f, den2 = 0.f, den3 = 0.f;
    float acc0 = 0.f, acc1 = 0.f;
    for (int i = beg; i < end; ++i) {
        float4 w4 = *reinterpret_cast<const float4*>(&wbuf[(size_t)i * 4]);
        den0 += w4.x; den1 += w4.y; den2 += w4.z; den3 += w4.w;
        int sn = cols[i];
        const float* hp = hs + (size_t)sn * 128;
        float wA = (lane < 32) ? w4.x : w4.y;
        float wB = (lane < 32) ? w4.z : w4.w;
        acc0 = fmaf(wA, hp[lane], acc0);
        acc1 = fmaf(wB, hp[64 + lane], acc1);
    }
    den0 += 1e-16f; den1 += 1e-16f; den2 += 1e-16f; den3 += 1e-16f;
    float d0 = lane < 32 ? den0 : den1;
    float d1 = lane < 32 ? den2 : den3;
    float v0 = fmaxf(acc0 / d0 + bias[lane], 0.f);
    float v1 = fmaxf(acc1 / d1 + bias[64 + lane], 0.f);
    float sum = v0 + __shfl_xor(v0, 32, 64) + v1 + __shfl_xor(v1, 32, 64);
    // every lane l now holds x[col = l&31] = 0.25*sum
    float xv = 0.25f * sum;

    float pp = xv * pW[lane & 31];
    pp += __shfl_xor(pp, 1, 64);
    pp += __shfl_xor(pp, 2, 64);
    pp += __shfl_xor(pp, 4, 64);
    pp += __shfl_xor(pp, 8, 64);
    pp += __shfl_xor(pp, 16, 64);
    float sc = __expf(pp + pb[0]);

    float accf = 0.f;
#pragma unroll
    for (int k = 0; k < 32; ++k) {
        float xk = __shfl(xv, k, 64);
        accf = fmaf(xk, fcW[k * 64 + lane], accf);
    }
    tab[(size_t)n * 64 + lane] = sc * accf;
}

// ---------------- link classifier: table gather + reduce ------------------
__global__ __launch_bounds__(256) void link_kernel(
    const float* __restrict__ Ad, const float* __restrict__ Bl,
    const int* __restrict__ eli,
    const float* __restrict__ fc1b, const float* __restrict__ fc2W,
    const float* __restrict__ fc2b,
    float* __restrict__ out, int EL)
{
    int wid = (blockIdx.x * 256 + threadIdx.x) >> 6;
    if (wid >= EL) return;
    int lane = threadIdx.x & 63;
    int e0 = eli[wid];
    int e1 = eli[EL + wid];
    float v = Ad[(size_t)e0 * 64 + lane] + Bl[(size_t)e1 * 64 + lane] + fc1b[lane];
    v = fmaxf(v, 0.f);
    float p = v * fc2W[lane];
#pragma unroll
    for (int off = 32; off >= 1; off >>= 1) p += __shfl_xor(p, off, 64);
    if (lane == 0) out[wid] = p + fc2b[0];
}

// ---------------------------------------------------------------------------
extern "C" void kernel_launch(void* const* d_in, const int* in_sizes, int n_in,
                              void* d_out, int out_size, void* d_ws, size_t ws_size,
                              hipStream_t stream)
{
    const int N  = in_sizes[6] / 128;
    const int Kd = in_sizes[2] / 128;   // 412
    const int Kl = in_sizes[4] / 128;   // 240
    const int KdP = (Kd + 31) & ~31;    // 416
    const int KlP = (Kl + 31) & ~31;    // 256
    const int E  = in_sizes[48] / 2;
    const int EL = in_sizes[49] / 2;

    const float* x_d    = (const float*)d_in[0];
    const float* x_l    = (const float*)d_in[1];
    const float* Wd_lin = (const float*)d_in[2];
    const float* bd_lin = (const float*)d_in[3];
    const float* Wl_lin = (const float*)d_in[4];
    const float* bl_lin = (const float*)d_in[5];
    const float* emb_d  = (const float*)d_in[6];
    const float* emb_l  = (const float*)d_in[7];

    const float *gWs[6], *gWd[6], *gas[6], *gad[6], *gb[6];
    for (int g = 0; g < 6; ++g) {
        gWs[g] = (const float*)d_in[8 + 5 * g + 0];
        gWd[g] = (const float*)d_in[8 + 5 * g + 1];
        gas[g] = (const float*)d_in[8 + 5 * g + 2];
        gad[g] = (const float*)d_in[8 + 5 * g + 3];
        gb[g]  = (const float*)d_in[8 + 5 * g + 4];
    }
    const float* pen_Wd = (const float*)d_in[38];
    const float* pen_bd = (const float*)d_in[39];
    const float* pen_Wl = (const float*)d_in[40];
    const float* pen_bl = (const float*)d_in[41];
    const float* fc1W   = (const float*)d_in[42];
    const float* fc1b   = (const float*)d_in[43];
    const float* fc2W   = (const float*)d_in[44];
    const float* fc2b   = (const float*)d_in[45];
    const int* node_id_d = (const int*)d_in[46];
    const int* node_id_l = (const int*)d_in[47];
    const int* ei  = (const int*)d_in[48];
    const int* eli = (const int*)d_in[49];
    const int* s_arr = ei;
    const int* t_arr = ei + E;

    // ---- workspace carve-up ----
    char* ws = (char*)d_ws;
    size_t off = 0;
    auto alloc = [&](size_t bytes) -> char* {
        char* p = ws + off;
        off = (off + bytes + 255) & ~(size_t)255;
        return p;
    };
    float* bufd0 = (float*)alloc((size_t)N * 128 * 4);
    float* bufd1 = (float*)alloc((size_t)N * 128 * 4);
    float* bufl0 = (float*)alloc((size_t)N * 128 * 4);
    float* bufl1 = (float*)alloc((size_t)N * 128 * 4);
    // region1 (N*2048 B): aggp0 | hs_d + hs_l
    char* region1 = alloc((size_t)N * 2048);
    u16* aggp0  = (u16*)region1;
    float* hs_d = (float*)region1;
    float* hs_l = (float*)(region1 + (size_t)N * 512);
    // weight planes
    u16* btWd = (u16*)alloc((size_t)2 * 128 * KdP * 2);
    u16* btWl = (u16*)alloc((size_t)2 * 128 * KlP * 2);
    u16* btWs[6];
    for (int g = 0; g < 6; ++g) {
        int J = (g < 4) ? 512 : 128;
        btWs[g] = (u16*)alloc((size_t)2 * J * 128 * 2);
    }
    float* es1  = (float*)alloc((size_t)N * 4 * 4);
    float* ed1  = (float*)alloc((size_t)N * 4 * 4);
    float* es2  = (float*)alloc((size_t)N * 4 * 4);
    float* ed2  = (float*)alloc((size_t)N * 4 * 4);
    float* Uall = (float*)alloc((size_t)6 * 1024 * 4);
    int* rpt_t = (int*)alloc((size_t)(N + 1) * 4);
    int* rpt_s = (int*)alloc((size_t)(N + 1) * 4);
    // zero-initialized block: deg_t | deg_s | cur_t | cur_s  (ONE memset)
    int* zero4 = (int*)alloc((size_t)4 * N * 4);
    int* deg_t = zero4;
    int* deg_s = zero4 + N;
    int* cur_t = zero4 + 2 * (size_t)N;
    int* cur_s = zero4 + 3 * (size_t)N;
    int* col_t = (int*)alloc((size_t)E * 4);
    int* col_s = (int*)alloc((size_t)E * 4);
    int* row_t = (int*)alloc((size_t)E * 4);
    int* row_s = (int*)alloc((size_t)E * 4);
    float* w_t = (float*)alloc((size_t)E * 4 * 4);
    float* w_s = (float*)alloc((size_t)E * 4 * 4);
    int* bs_t  = (int*)alloc(256 * 4);
    int* bs_s  = (int*)alloc(256 * 4);
    int* bo_t  = (int*)alloc(257 * 4);
    int* bo_s  = (int*)alloc(257 * 4);
    float* Ad  = (float*)alloc((size_t)N * 64 * 4);
    float* Bl  = (float*)alloc((size_t)N * 64 * 4);
    // optional second agg buffer for merged layer-1/2 pairs
    bool dual = (off + (size_t)N * 2048 + 256) <= ws_size;
    u16* aggp1 = dual ? (u16*)alloc((size_t)N * 2048) : aggp0;

    hipMemsetAsync(zero4, 0, (size_t)4 * N * 4, stream);

    dim3 blk(256);
    const int n64 = (N + 63) / 64;
    const int nEB = (E + 255) / 256;
    const int nAB = (N + 3) / 4;

    // ---- fused: ALL weight splits || compute_U ----
    {
        SplitJobs SJ;
        const float* srcs[8] = {Wd_lin, Wl_lin, gWs[0], gWs[1], gWs[2], gWs[3], gWs[4], gWs[5]};
        u16* dsts[8] = {btWd, btWl, btWs[0], btWs[1], btWs[2], btWs[3], btWs[4], btWs[5]};
        int Ks[8]  = {Kd, Kl, 128, 128, 128, 128, 128, 128};
        int Kps[8] = {KdP, KlP, 128, 128, 128, 128, 128, 128};
        int Js[8]  = {128, 128, 512, 512, 512, 512, 128, 128};
        int acc = 0;
        for (int j = 0; j < 8; ++j) {
            SJ.src[j] = srcs[j]; SJ.dst[j] = dsts[j];
            SJ.K[j] = Ks[j]; SJ.Kp[j] = Kps[j]; SJ.J[j] = Js[j];
            SJ.offs[j] = acc;
            acc += Js[j] * Kps[j];
        }
        SJ.offs[8] = acc;
        UParams up;
        for (int g = 0; g < 6; ++g) {
            up.Ws[g] = gWs[g]; up.Wd[g] = gWd[g];
            up.as_[g] = gas[g]; up.ad_[g] = gad[g];
            up.C[g] = (g < 4) ? 128 : 32;
        }
        int gx = (acc + 255) / 256;
        if (gx < 1536) gx = 1536;
        k_split_U<<<dim3(gx, 2), blk, 0, stream>>>(SJ, up, Uall);
    }

    // ---- fused: input GEMM pair (+layer-1 es/ed) || degree count ----
    {
        GemmPairF P;
        P.A0 = x_d; P.B0 = btWd; P.bias0 = bd_lin; P.emb0 = emb_d;
        P.ids0 = node_id_d; P.C0 = bufd0; P.K0 = Kd; P.Kp0 = KdP;
        P.A1 = x_l; P.B1 = btWl; P.bias1 = bl_lin; P.emb1 = emb_l;
        P.ids1 = node_id_l; P.C1 = bufl0; P.K1 = Kl; P.Kp1 = KlP;
        int gx = (n64 > nEB) ? n64 : nEB;
        k_gemm_input_deg<<<dim3(gx, 3), blk, 0, stream>>>(
            P, N, n64, s_arr, t_arr, deg_t, deg_s, E,
            Uall + 0 * 1024, Uall + 1 * 1024, es1, ed1, es2, ed2);
    }

    // ---- CSR scans + fill ----
    {
        int nb = (N + 255) / 256;
        scan_partial<<<dim3(nb, 2), blk, 0, stream>>>(deg_t, deg_s, rpt_t, rpt_s, bs_t, bs_s, N);
        scan_bsums<<<dim3(1, 2), blk, 0, stream>>>(bs_t, bs_s, bo_t, bo_s, nb);
        scan_add<<<dim3(nb, 2), blk, 0, stream>>>(rpt_t, rpt_s, bo_t, bo_s, N, nb);
        fill_kernel<<<dim3(nEB), blk, 0, stream>>>(s_arr, t_arr, rpt_t, rpt_s,
                                                   cur_t, cur_s, col_t, col_s,
                                                   row_t, row_s, E);
    }

    float* xd_cur = bufd0; float* xl_cur = bufl0;
    float* xd_nxt = bufd1; float* xl_nxt = bufl1;

    for (int L = 0; L < 2; ++L) {
        const int gd = 2 * L, gl = 2 * L + 1;
        const int gd2 = 2 * (L + 1), gl2 = 2 * (L + 1) + 1;   // next layer U

        edge_w_kernel<<<dim3(nEB, 2), blk, 0, stream>>>(
            col_t, row_t, col_s, row_s, es1, ed1, es2, ed2, w_t, w_s, E);

        if (dual) {
            AggXPair AP;
            AP.rpt0 = rpt_t; AP.col0 = col_t; AP.w0 = w_t; AP.x0 = xd_cur; AP.out0 = aggp0;
            AP.rpt1 = rpt_s; AP.col1 = col_s; AP.w1 = w_s; AP.x1 = xl_cur; AP.out1 = aggp1;
            agg_x2<<<dim3(nAB, 2), blk, 0, stream>>>(AP, N);

            HeadsPair HP;
            HP.A0 = aggp0; HP.B0 = btWs[gd]; HP.bias0 = gb[gd]; HP.C0 = xl_nxt; HP.xl0 = 1;
            HP.A1 = aggp1; HP.B1 = btWs[gl]; HP.bias1 = gb[gl]; HP.C1 = xd_nxt; HP.xl1 = 0;
            HP.U1n = Uall + gd2 * 1024; HP.U2n = Uall + gl2 * 1024;
            HP.es1 = es1; HP.ed1 = ed1; HP.es2 = es2; HP.ed2 = ed2;
            gemm_heads2<<<dim3(n64, 2), blk, 0, stream>>>(HP, N);
        } else {
            AggXPair AP;
            AP.rpt0 = rpt_t; AP.col0 = col_t; AP.w0 = w_t; AP.x0 = xd_cur; AP.out0 = aggp0;
            AP.rpt1 = AP.rpt0; AP.col1 = AP.col0; AP.w1 = AP.w0; AP.x1 = AP.x0; AP.out1 = AP.out0;
            agg_x2<<<dim3(nAB, 1), blk, 0, stream>>>(AP, N);
            HeadsPair HP;
            HP.A0 = aggp0; HP.B0 = btWs[gd]; HP.bias0 = gb[gd]; HP.C0 = xl_nxt; HP.xl0 = 1;
            HP.A1 = HP.A0; HP.B1 = HP.B0; HP.bias1 = HP.bias0; HP.C1 = HP.C0; HP.xl1 = 1;
            HP.U1n = Uall + gd2 * 1024; HP.U2n = Uall + gl2 * 1024;
            HP.es1 = es1; HP.ed1 = ed1; HP.es2 = es2; HP.ed2 = ed2;
            gemm_heads2<<<dim3(n64, 1), blk, 0, stream>>>(HP, N);

            AP.rpt0 = rpt_s; AP.col0 = col_s; AP.w0 = w_s; AP.x0 = xl_cur; AP.out0 = aggp0;
            AP.rpt1 = AP.rpt0; AP.col1 = AP.col0; AP.w1 = AP.w0; AP.x1 = AP.x0; AP.out1 = AP.out0;
            agg_x2<<<dim3(nAB, 1), blk, 0, stream>>>(AP, N);
            HP.A0 = aggp0; HP.B0 = btWs[gl]; HP.bias0 = gb[gl]; HP.C0 = xd_nxt; HP.xl0 = 0;
            HP.A1 = HP.A0; HP.B1 = HP.B0; HP.bias1 = HP.bias0; HP.C1 = HP.C0; HP.xl1 = 0;
            gemm_heads2<<<dim3(n64, 1), blk, 0, stream>>>(HP, N);
        }

        float* tmp;
        tmp = xd_cur; xd_cur = xd_nxt; xd_nxt = tmp;
        tmp = xl_cur; xl_cur = xl_nxt; xl_nxt = tmp;
    }

    // ---- layer 3: GEMM pair, edge_w, fused agg+penalty+fc1 ----
    {
        const int gd = 4, gl = 5;

        GemmPairF P;
        P.A0 = xd_cur; P.B0 = btWs[gd]; P.bias0 = nullptr; P.emb0 = nullptr;
        P.ids0 = nullptr; P.C0 = hs_d; P.K0 = 128; P.Kp0 = 128;
        P.A1 = xl_cur; P.B1 = btWs[gl]; P.bias1 = nullptr; P.emb1 = nullptr;
        P.ids1 = nullptr; P.C1 = hs_l; P.K1 = 128; P.Kp1 = 128;
        k_gemm_l3<<<dim3(n64, 2), blk, 0, stream>>>(P, N);

        edge_w_kernel<<<dim3(nEB, 2), blk, 0, stream>>>(
            col_t, row_t, col_s, row_s, es1, ed1, es2, ed2, w_t, w_s, E);

        Agg128Pair AP;
        AP.rpt0 = rpt_t; AP.col0 = col_t; AP.w0 = w_t;
        AP.hs0 = hs_d; AP.bias0 = gb[gd];
        AP.pW0 = pen_Wl; AP.pb0 = pen_bl; AP.fcW0 = fc1W + 32 * 64; AP.tab0 = Bl;
        AP.rpt1 = rpt_s; AP.col1 = col_s; AP.w1 = w_s;
        AP.hs1 = hs_l; AP.bias1 = gb[gl];
        AP.pW1 = pen_Wd; AP.pb1 = pen_bd; AP.fcW1 = fc1W; AP.tab1 = Ad;
        gat_agg128_fc1<<<dim3(nAB, 2), blk, 0, stream>>>(AP, N);
    }

    // link classifier on supervision edges
    link_kernel<<<dim3((EL + 3) / 4), blk, 0, stream>>>(
        Ad, Bl, eli, fc1b, fc2W, fc2b, (float*)d_out, EL);
}

// Round 18
// 764.960 us; speedup vs baseline: 1.0688x; 1.0688x over previous
//
#include <hip/hip_runtime.h>
#include <hip/hip_bf16.h>
#include <math.h>

typedef unsigned short u16;
typedef __bf16 bf16x8 __attribute__((ext_vector_type(8)));
typedef float f32x4 __attribute__((ext_vector_type(4)));

// ---------------------------------------------------------------------------
// Hetero-GAT forward, bf16 hi/lo split MFMA.
//  - agg<->GEMM commute for layers 1-2; per-edge softmax weights precomputed.
//  - r13-proven BM=64 GEMM structure (untouched).
//  - r16-proven dispatch fusion: splitBt||computeU, inputGEMM||deg,
//    fill||es_ed2(L1), L3GEMM||es_ed2(L3).
//  - r17-keep: penalty+fc1 fused into layer-3 aggregation tail (fc1_halves
//    deleted). r17-revert: es/ed GEMM epilogue (3.2M bank conflicts, -40us).
// ---------------------------------------------------------------------------

__device__ inline float bfbits2f(u16 u) {
    unsigned int v = ((unsigned int)u) << 16;
    float f;
    __builtin_memcpy(&f, &v, 4);
    return f;
}
__device__ inline u16 f2bf(float x) {
    __hip_bfloat16 h = __float2bfloat16(x);
    u16 u;
    __builtin_memcpy(&u, &h, 2);
    return u;
}

#define GLD16(gp, lp) __builtin_amdgcn_global_load_lds( \
    (__attribute__((address_space(1))) void*)(gp),      \
    (__attribute__((address_space(3))) void*)(lp), 16, 0, 0)

// ---------------- shared structs -------------------------------------------
struct SplitJobs {
    const float* src[8];
    u16* dst[8];
    int K[8];
    int Kp[8];
    int J[8];
    int offs[9];
};

struct UParams {
    const float* Ws[6];
    const float* Wd[6];
    const float* as_[6];
    const float* ad_[6];
    int C[6];
};

struct GemmPairF {
    const float* A0; const u16* B0; const float* bias0;
    const float* emb0; const int* ids0; float* C0; int K0; int Kp0;
    const float* A1; const u16* B1; const float* bias1;
    const float* emb1; const int* ids1; float* C1; int K1; int Kp1;
};

// ---------------- GEMM body (r13-proven) -----------------------------------
template<bool BIAS_EMB>
__device__ __forceinline__ void gemm_f32a_body(
    const float* __restrict__ A, const u16* __restrict__ Bhi,
    const float* __restrict__ bias, const float* __restrict__ emb,
    const int* __restrict__ ids, float* __restrict__ C,
    int K, int Kp, int N)
{
    __shared__ __align__(16) u16 sAh[2048];   // 64 rows x 32 k
    __shared__ __align__(16) u16 sAl[2048];
    __shared__ __align__(16) u16 sBh[4096];   // 128 cols x 32 k
    __shared__ __align__(16) u16 sBl[4096];
    const int tid = threadIdx.x;
    const int lane = tid & 63;
    const int wid = tid >> 6;
    const int rowbase = blockIdx.x * 64;

    const u16* Blo = Bhi + (size_t)128 * Kp;
    const int nk = Kp / 32;

    const int ar = tid >> 2;
    const int ac = tid & 3;
    const int aswz = (ar >> 1) & 3;
    int gra = rowbase + ar; if (gra >= N) gra = N - 1;
    const size_t aoffA = (size_t)gra * K + (size_t)(ac * 8);
    const int asto = ar * 32 + ((ac ^ aswz) << 3);

    const int brow = tid >> 2;
    const int bkc = tid & 3;
    const int bswz = (brow >> 1) & 3;
    const size_t boff0 = (size_t)brow * Kp + (size_t)((bkc ^ bswz) * 8);
    const size_t boff1 = (size_t)(64 + brow) * Kp + (size_t)((bkc ^ bswz) * 8);

    const int kgs = ((lane >> 4) ^ ((lane >> 1) & 3)) * 8;
    const int arow_rd = lane & 15;
    const int brow_rd = wid * 32 + (lane & 15);

    f32x4 acc[4][2] = {};

    for (int ks = 0; ks < nk; ++ks) {
        const int k0 = ks * 32;
        GLD16(Bhi + boff0 + k0, &sBh[(size_t)tid * 8]);
        GLD16(Bhi + boff1 + k0, &sBh[(size_t)(tid + 256) * 8]);
        GLD16(Blo + boff0 + k0, &sBl[(size_t)tid * 8]);
        GLD16(Blo + boff1 + k0, &sBl[(size_t)(tid + 256) * 8]);
        float4 av0 = make_float4(0.f, 0.f, 0.f, 0.f);
        float4 av1 = make_float4(0.f, 0.f, 0.f, 0.f);
        const int kc = k0 + ac * 8;
        if (kc < K)     av0 = *reinterpret_cast<const float4*>(&A[aoffA + k0]);
        if (kc + 4 < K) av1 = *reinterpret_cast<const float4*>(&A[aoffA + k0 + 4]);
        float vv[8] = {av0.x, av0.y, av0.z, av0.w, av1.x, av1.y, av1.z, av1.w};
        u16 h[8], l[8];
#pragma unroll
        for (int j = 0; j < 8; ++j) {
            u16 hb = f2bf(vv[j]);
            h[j] = hb;
            l[j] = f2bf(vv[j] - bfbits2f(hb));
        }
        uint4 hp, lp;
        hp.x = (unsigned)h[0] | ((unsigned)h[1] << 16);
        hp.y = (unsigned)h[2] | ((unsigned)h[3] << 16);
        hp.z = (unsigned)h[4] | ((unsigned)h[5] << 16);
        hp.w = (unsigned)h[6] | ((unsigned)h[7] << 16);
        lp.x = (unsigned)l[0] | ((unsigned)l[1] << 16);
        lp.y = (unsigned)l[2] | ((unsigned)l[3] << 16);
        lp.z = (unsigned)l[4] | ((unsigned)l[5] << 16);
        lp.w = (unsigned)l[6] | ((unsigned)l[7] << 16);
        *reinterpret_cast<uint4*>(&sAh[asto]) = hp;
        *reinterpret_cast<uint4*>(&sAl[asto]) = lp;
        __syncthreads();
        bf16x8 bh[2], bl[2];
#pragma unroll
        for (int n = 0; n < 2; ++n) {
            bh[n] = *reinterpret_cast<const bf16x8*>(&sBh[(brow_rd + n * 16) * 32 + kgs]);
            bl[n] = *reinterpret_cast<const bf16x8*>(&sBl[(brow_rd + n * 16) * 32 + kgs]);
        }
#pragma unroll
        for (int m = 0; m < 4; ++m) {
            bf16x8 ah = *reinterpret_cast<const bf16x8*>(&sAh[(arow_rd + m * 16) * 32 + kgs]);
            bf16x8 al = *reinterpret_cast<const bf16x8*>(&sAl[(arow_rd + m * 16) * 32 + kgs]);
#pragma unroll
            for (int n = 0; n < 2; ++n) {
                acc[m][n] = __builtin_amdgcn_mfma_f32_16x16x32_bf16(ah, bh[n], acc[m][n], 0, 0, 0);
                acc[m][n] = __builtin_amdgcn_mfma_f32_16x16x32_bf16(ah, bl[n], acc[m][n], 0, 0, 0);
                acc[m][n] = __builtin_amdgcn_mfma_f32_16x16x32_bf16(al, bh[n], acc[m][n], 0, 0, 0);
            }
        }
        __syncthreads();
    }

#pragma unroll
    for (int m = 0; m < 4; ++m) {
        int rb = rowbase + m * 16 + ((lane >> 4) << 2);
#pragma unroll
        for (int i = 0; i < 4; ++i) {
            int r = rb + i;
            if (r >= N) continue;
            const float* ep = nullptr;
            if (BIAS_EMB) ep = emb + (size_t)ids[r] * 128;
#pragma unroll
            for (int n = 0; n < 2; ++n) {
                int col = wid * 32 + n * 16 + (lane & 15);
                float v = acc[m][n][i];
                if (BIAS_EMB) v += bias[col] + ep[col];
                C[(size_t)r * 128 + col] = v;
            }
        }
    }
}

__device__ __forceinline__ void es_ed2_body(
    const float* __restrict__ xd, const float* __restrict__ xl,
    const float* __restrict__ U1, const float* __restrict__ U2,
    float* __restrict__ es1, float* __restrict__ ed1,
    float* __restrict__ es2, float* __restrict__ ed2, int N, int t)
{
    if (t >= N * 16) return;
    int n = t >> 4, j = t & 15;
    const float4* X4 = reinterpret_cast<const float4*>(((j < 8) ? xd : xl) + (size_t)n * 128);
    const float* U;
    float* dst;
    int col;
    if (j < 4)       { U = U1; col = j;      dst = &es1[n * 4 + j]; }
    else if (j < 8)  { U = U2; col = j;      dst = &ed2[n * 4 + (j - 4)]; }
    else if (j < 12) { U = U1; col = j - 4;  dst = &ed1[n * 4 + (j - 8)]; }
    else             { U = U2; col = j - 12; dst = &es2[n * 4 + (j - 12)]; }
    float s = 0.f;
#pragma unroll 8
    for (int k4 = 0; k4 < 32; ++k4) {
        float4 x = X4[k4];
        s = fmaf(x.x, U[(k4 * 4 + 0) * 8 + col], s);
        s = fmaf(x.y, U[(k4 * 4 + 1) * 8 + col], s);
        s = fmaf(x.z, U[(k4 * 4 + 2) * 8 + col], s);
        s = fmaf(x.w, U[(k4 * 4 + 3) * 8 + col], s);
    }
    *dst = s;
}

// ---------------- fused: weight splits || compute_U ------------------------
__global__ __launch_bounds__(256) void k_split_U(SplitJobs SJ, UParams P,
                                                 float* __restrict__ U)
{
    if (blockIdx.y == 0) {
        int t = blockIdx.x * 256 + threadIdx.x;
        if (t >= SJ.offs[8]) return;
        int j = 0;
#pragma unroll
        for (int q = 1; q < 8; ++q) if (t >= SJ.offs[q]) j = q;
        int e = t - SJ.offs[j];
        int Kp = SJ.Kp[j], K = SJ.K[j], J = SJ.J[j];
        const float* B = SJ.src[j];
        u16* hi = SJ.dst[j];
        int col = e / Kp, k = e - col * Kp;
        float v = (k < K) ? B[(size_t)k * J + col] : 0.f;
        u16 hb = f2bf(v);
        hi[e] = hb;
        hi[(size_t)J * Kp + e] = f2bf(v - bfbits2f(hb));
        return;
    }
    int w = (blockIdx.x * 256 + threadIdx.x) >> 6;
    if (w >= 6144) return;
    int lane = threadIdx.x & 63;
    int g = w >> 10;
    int o = w & 1023;
    int k = o >> 3, j = o & 7, h = j & 3;
    int C = P.C[g];
    int HC = 4 * C;
    const float* W = (j < 4) ? P.Ws[g] : P.Wd[g];
    const float* a = (j < 4) ? P.as_[g] : P.ad_[g];
    float s = 0.f;
    for (int c = lane; c < C; c += 64)
        s = fmaf(W[k * HC + h * C + c], a[h * C + c], s);
#pragma unroll
    for (int off = 32; off >= 1; off >>= 1) s += __shfl_xor(s, off, 64);
    if (lane == 0) U[g * 1024 + o] = s;
}

// ---------------- fused: input GEMM pair || degree count -------------------
__global__ __launch_bounds__(256) void k_gemm_input_deg(
    GemmPairF P, int N, int n64,
    const int* __restrict__ s, const int* __restrict__ t,
    int* __restrict__ deg_t, int* __restrict__ deg_s, int E)
{
    if (blockIdx.y < 2) {
        if ((int)blockIdx.x >= n64) return;
        if (blockIdx.y == 0)
            gemm_f32a_body<true>(P.A0, P.B0, P.bias0, P.emb0, P.ids0, P.C0, P.K0, P.Kp0, N);
        else
            gemm_f32a_body<true>(P.A1, P.B1, P.bias1, P.emb1, P.ids1, P.C1, P.K1, P.Kp1, N);
        return;
    }
    int i = blockIdx.x * 256 + threadIdx.x;
    if (i >= E) return;
    atomicAdd(&deg_t[t[i]], 1);
    atomicAdd(&deg_s[s[i]], 1);
}

// ---------------- fused: layer-3 GEMM pair || es_ed2 -----------------------
__global__ __launch_bounds__(256) void k_gemm_l3_esed(
    GemmPairF P, int N, int n64,
    const float* __restrict__ xd, const float* __restrict__ xl,
    const float* __restrict__ U1, const float* __restrict__ U2,
    float* __restrict__ es1, float* __restrict__ ed1,
    float* __restrict__ es2, float* __restrict__ ed2)
{
    if (blockIdx.y < 2) {
        if ((int)blockIdx.x >= n64) return;
        if (blockIdx.y == 0)
            gemm_f32a_body<false>(P.A0, P.B0, P.bias0, P.emb0, P.ids0, P.C0, P.K0, P.Kp0, N);
        else
            gemm_f32a_body<false>(P.A1, P.B1, P.bias1, P.emb1, P.ids1, P.C1, P.K1, P.Kp1, N);
        return;
    }
    es_ed2_body(xd, xl, U1, U2, es1, ed1, es2, ed2, N,
                blockIdx.x * 256 + threadIdx.x);
}

// ---------------- scans ----------------------------------------------------
__global__ void scan_partial(const int* dA, const int* dB, int* eA, int* eB,
                             int* bsA, int* bsB, int N)
{
    __shared__ int lds[256];
    const int* deg = blockIdx.y ? dB : dA;
    int* ex = blockIdx.y ? eB : eA;
    int* bs = blockIdx.y ? bsB : bsA;
    int i = blockIdx.x * 256 + threadIdx.x;
    int v = (i < N) ? deg[i] : 0;
    int x = v;
    lds[threadIdx.x] = x;
    __syncthreads();
    for (int off = 1; off < 256; off <<= 1) {
        int tv = (threadIdx.x >= off) ? lds[threadIdx.x - off] : 0;
        __syncthreads();
        x += tv;
        lds[threadIdx.x] = x;
        __syncthreads();
    }
    if (i < N) ex[i] = x - v;
    if (threadIdx.x == 255) bs[blockIdx.x] = x;
}

__global__ void scan_bsums(int* bsA, int* bsB, int* boA, int* boB, int nb)
{
    __shared__ int lds[256];
    int* bs = blockIdx.y ? bsB : bsA;
    int* bo = blockIdx.y ? boB : boA;
    int v = (threadIdx.x < nb) ? bs[threadIdx.x] : 0;
    int x = v;
    lds[threadIdx.x] = x;
    __syncthreads();
    for (int off = 1; off < 256; off <<= 1) {
        int tv = (threadIdx.x >= off) ? lds[threadIdx.x - off] : 0;
        __syncthreads();
        x += tv;
        lds[threadIdx.x] = x;
        __syncthreads();
    }
    if (threadIdx.x < nb) bo[threadIdx.x] = x - v;
    if (threadIdx.x == 255) bo[nb] = x;
}

__global__ void scan_add(int* eA, int* eB, const int* boA, const int* boB, int N, int nb)
{
    int* ex = blockIdx.y ? eB : eA;
    const int* bo = blockIdx.y ? boB : boA;
    int i = blockIdx.x * 256 + threadIdx.x;
    if (i < N) ex[i] += bo[i >> 8];
    if (i == 0) ex[N] = bo[nb];
}

// ---------------- fused: CSR fill || es_ed2 (layer 1) ----------------------
__global__ __launch_bounds__(256) void k_fill_esed(
    const int* __restrict__ s, const int* __restrict__ t,
    const int* __restrict__ rpt_t, const int* __restrict__ rpt_s,
    int* __restrict__ cur_t, int* __restrict__ cur_s,
    int* __restrict__ col_t, int* __restrict__ col_s,
    int* __restrict__ row_t, int* __restrict__ row_s, int E,
    const float* __restrict__ xd, const float* __restrict__ xl,
    const float* __restrict__ U1, const float* __restrict__ U2,
    float* __restrict__ es1, float* __restrict__ ed1,
    float* __restrict__ es2, float* __restrict__ ed2, int N)
{
    if (blockIdx.y == 0) {
        int i = blockIdx.x * 256 + threadIdx.x;
        if (i >= E) return;
        int sv = s[i], tv = t[i];
        int p = atomicAdd(&cur_t[tv], 1);
        int pos = rpt_t[tv] + p;
        col_t[pos] = sv; row_t[pos] = tv;
        p = atomicAdd(&cur_s[sv], 1);
        pos = rpt_s[sv] + p;
        col_s[pos] = tv; row_s[pos] = sv;
        return;
    }
    es_ed2_body(xd, xl, U1, U2, es1, ed1, es2, ed2, N,
                blockIdx.x * 256 + threadIdx.x);
}

// ---------------- standalone es_ed2 (layer 2) ------------------------------
__global__ void es_ed2_kernel(const float* __restrict__ xd, const float* __restrict__ xl,
                              const float* __restrict__ U1, const float* __restrict__ U2,
                              float* __restrict__ es1, float* __restrict__ ed1,
                              float* __restrict__ es2, float* __restrict__ ed2, int N)
{
    es_ed2_body(xd, xl, U1, U2, es1, ed1, es2, ed2, N,
                blockIdx.x * blockDim.x + threadIdx.x);
}

// ---------------- per-edge softmax weights (no-max, CSR order) ------------
__global__ __launch_bounds__(256) void edge_w_kernel(
    const int* __restrict__ col_t, const int* __restrict__ row_t,
    const int* __restrict__ col_s, const int* __restrict__ row_s,
    const float* __restrict__ es1, const float* __restrict__ ed1,
    const float* __restrict__ es2, const float* __restrict__ ed2,
    float* __restrict__ w_t, float* __restrict__ w_s, int E)
{
    int i = blockIdx.x * 256 + threadIdx.x;
    if (i >= E) return;
    const int* col; const int* row; const float* es; const float* ed; float* w;
    if (blockIdx.y == 0) { col = col_t; row = row_t; es = es1; ed = ed1; w = w_t; }
    else                 { col = col_s; row = row_s; es = es2; ed = ed2; w = w_s; }
    int sn = col[i], rn = row[i];
    float4 a = *reinterpret_cast<const float4*>(&es[(size_t)sn * 4]);
    float4 b = *reinterpret_cast<const float4*>(&ed[(size_t)rn * 4]);
    float v0 = a.x + b.x; v0 = v0 > 0.f ? v0 : 0.2f * v0;
    float v1 = a.y + b.y; v1 = v1 > 0.f ? v1 : 0.2f * v1;
    float v2 = a.z + b.z; v2 = v2 > 0.f ? v2 : 0.2f * v2;
    float v3 = a.w + b.w; v3 = v3 > 0.f ? v3 : 0.2f * v3;
    float4 o;
    o.x = __expf(v0); o.y = __expf(v1); o.z = __expf(v2); o.w = __expf(v3);
    *reinterpret_cast<float4*>(&w[(size_t)i * 4]) = o;
}

// ---------------- per-head x-aggregation pair (layers 1-2) ----------------
struct AggXPair {
    const int* rpt0; const int* col0; const float* w0; const float* x0; u16* out0;
    const int* rpt1; const int* col1; const float* w1; const float* x1; u16* out1;
};

__global__ __launch_bounds__(256) void agg_x2(AggXPair P, int Ndst)
{
    int n = blockIdx.x * 4 + (threadIdx.x >> 6);
    if (n >= Ndst) return;
    const bool y1 = (blockIdx.y == 1);
    const int* rowptr  = y1 ? P.rpt1 : P.rpt0;
    const int* cols    = y1 ? P.col1 : P.col0;
    const float* wbuf  = y1 ? P.w1 : P.w0;
    const float* xsrc  = y1 ? P.x1 : P.x0;
    u16* aggp          = y1 ? P.out1 : P.out0;

    int lane = threadIdx.x & 63;
    int beg = rowptr[n], end = rowptr[n + 1];

    float den0 = 0.f, den1 = 0.f, den2 = 0.f, den3 = 0.f;
    float2 acc[4] = {};

    for (int i = beg; i < end; ++i) {
        float4 w4 = *reinterpret_cast<const float4*>(&wbuf[(size_t)i * 4]);
        den0 += w4.x; den1 += w4.y; den2 += w4.z; den3 += w4.w;
        int sn = cols[i];
        float2 xv = *reinterpret_cast<const float2*>(&xsrc[(size_t)sn * 128 + 2 * lane]);
        acc[0].x = fmaf(w4.x, xv.x, acc[0].x); acc[0].y = fmaf(w4.x, xv.y, acc[0].y);
        acc[1].x = fmaf(w4.y, xv.x, acc[1].x); acc[1].y = fmaf(w4.y, xv.y, acc[1].y);
        acc[2].x = fmaf(w4.z, xv.x, acc[2].x); acc[2].y = fmaf(w4.z, xv.y, acc[2].y);
        acc[3].x = fmaf(w4.w, xv.x, acc[3].x); acc[3].y = fmaf(w4.w, xv.y, acc[3].y);
    }

    float inv[4] = {1.f / (den0 + 1e-16f), 1.f / (den1 + 1e-16f),
                    1.f / (den2 + 1e-16f), 1.f / (den3 + 1e-16f)};
    u16* lo = aggp + (size_t)Ndst * 512;
    size_t base = (size_t)n * 512 + 2 * lane;
#pragma unroll
    for (int h = 0; h < 4; ++h) {
        float v0 = acc[h].x * inv[h];
        float v1 = acc[h].y * inv[h];
        u16 h0 = f2bf(v0), h1 = f2bf(v1);
        *reinterpret_cast<unsigned*>(&aggp[base + h * 128]) =
            (unsigned)h0 | ((unsigned)h1 << 16);
        u16 l0 = f2bf(v0 - bfbits2f(h0)), l1 = f2bf(v1 - bfbits2f(h1));
        *reinterpret_cast<unsigned*>(&lo[base + h * 128]) =
            (unsigned)l0 | ((unsigned)l1 << 16);
    }
}

// ---------------- head-blocked GEMM pair + relu/head-mean epilogue --------
struct HeadsPair {
    const u16* A0; const u16* B0; const float* bias0; float* C0;
    const u16* A1; const u16* B1; const float* bias1; float* C1;
};

__global__ __launch_bounds__(256) void gemm_heads2(HeadsPair P, int N)
{
    __shared__ __align__(16) u16 sAh[2048];
    __shared__ __align__(16) u16 sAl[2048];
    __shared__ __align__(16) u16 sBh[4096];
    __shared__ __align__(16) u16 sBl[4096];
    const int tid = threadIdx.x;
    const int lane = tid & 63;
    const int wid = tid >> 6;
    const int rowbase = blockIdx.x * 64;

    const bool y1 = (blockIdx.y == 1);
    const u16* Ahi = y1 ? P.A1 : P.A0;
    const u16* Bhi = y1 ? P.B1 : P.B0;
    const float* bias = y1 ? P.bias1 : P.bias0;
    float* C = y1 ? P.C1 : P.C0;

    const u16* Alo = Ahi + (size_t)N * 512;
    const u16* Blo = Bhi + (size_t)512 * 128;

    const int akc = tid & 3;
    const int arow = tid >> 2;
    const int swz = (arow >> 1) & 3;
    int gr = rowbase + arow; if (gr >= N) gr = N - 1;
    const size_t aoff  = (size_t)gr * 512 + (size_t)((akc ^ swz) * 8);
    const size_t boff0 = (size_t)arow * 128 + (size_t)((akc ^ swz) * 8);
    const size_t boff1 = (size_t)(64 + arow) * 128 + (size_t)((akc ^ swz) * 8);

    const int kgs = ((lane >> 4) ^ ((lane >> 1) & 3)) * 8;
    const int arow_rd = lane & 15;
    const int brow_rd = wid * 32 + (lane & 15);

    f32x4 acc[4][2] = {};
    f32x4 runsum[4][2] = {};

    for (int h = 0; h < 4; ++h) {
        const size_t ha = (size_t)h * 128;
        const size_t hb = (size_t)h * 128 * 128;
#pragma unroll
        for (int ks = 0; ks < 4; ++ks) {
            const int k0 = ks * 32;
            GLD16(Ahi + aoff + ha + k0,  &sAh[(size_t)tid * 8]);
            GLD16(Alo + aoff + ha + k0,  &sAl[(size_t)tid * 8]);
            GLD16(Bhi + boff0 + hb + k0, &sBh[(size_t)tid * 8]);
            GLD16(Bhi + boff1 + hb + k0, &sBh[(size_t)(tid + 256) * 8]);
            GLD16(Blo + boff0 + hb + k0, &sBl[(size_t)tid * 8]);
            GLD16(Blo + boff1 + hb + k0, &sBl[(size_t)(tid + 256) * 8]);
            __syncthreads();
            bf16x8 bh[2], bl[2];
#pragma unroll
            for (int n = 0; n < 2; ++n) {
                bh[n] = *reinterpret_cast<const bf16x8*>(&sBh[(brow_rd + n * 16) * 32 + kgs]);
                bl[n] = *reinterpret_cast<const bf16x8*>(&sBl[(brow_rd + n * 16) * 32 + kgs]);
            }
#pragma unroll
            for (int m = 0; m < 4; ++m) {
                bf16x8 ah = *reinterpret_cast<const bf16x8*>(&sAh[(arow_rd + m * 16) * 32 + kgs]);
                bf16x8 al = *reinterpret_cast<const bf16x8*>(&sAl[(arow_rd + m * 16) * 32 + kgs]);
#pragma unroll
                for (int n = 0; n < 2; ++n) {
                    acc[m][n] = __builtin_amdgcn_mfma_f32_16x16x32_bf16(ah, bh[n], acc[m][n], 0, 0, 0);
                    acc[m][n] = __builtin_amdgcn_mfma_f32_16x16x32_bf16(ah, bl[n], acc[m][n], 0, 0, 0);
                    acc[m][n] = __builtin_amdgcn_mfma_f32_16x16x32_bf16(al, bh[n], acc[m][n], 0, 0, 0);
                }
            }
            __syncthreads();
        }
#pragma unroll
        for (int m = 0; m < 4; ++m)
#pragma unroll
            for (int n = 0; n < 2; ++n) {
                int col = wid * 32 + n * 16 + (lane & 15);
                float b = bias[h * 128 + col];
#pragma unroll
                for (int i = 0; i < 4; ++i) {
                    runsum[m][n][i] += fmaxf(acc[m][n][i] + b, 0.f);
                    acc[m][n][i] = 0.f;
                }
            }
    }

#pragma unroll
    for (int m = 0; m < 4; ++m) {
        int rb = rowbase + m * 16 + ((lane >> 4) << 2);
#pragma unroll
        for (int i = 0; i < 4; ++i) {
            int r = rb + i;
            if (r >= N) continue;
#pragma unroll
            for (int n = 0; n < 2; ++n) {
                int col = wid * 32 + n * 16 + (lane & 15);
                C[(size_t)r * 128 + col] = 0.25f * runsum[m][n][i];
            }
        }
    }
}

// ---------------- layer-3 aggregation + fused penalty/fc1 tables -----------
struct Agg128Pair {
    const int* rpt0; const int* col0; const float* w0;
    const float* hs0; const float* bias0;
    const float* pW0; const float* pb0; const float* fcW0; float* tab0;
    const int* rpt1; const int* col1; const float* w1;
    const float* hs1; const float* bias1;
    const float* pW1; const float* pb1; const float* fcW1; float* tab1;
};

__global__ __launch_bounds__(256) void gat_agg128_fc1(Agg128Pair P, int Ndst)
{
    int n = blockIdx.x * 4 + (threadIdx.x >> 6);
    if (n >= Ndst) return;
    const bool y1 = (blockIdx.y == 1);
    const int* rowptr = y1 ? P.rpt1 : P.rpt0;
    const int* cols   = y1 ? P.col1 : P.col0;
    const float* wbuf = y1 ? P.w1 : P.w0;
    const float* hs   = y1 ? P.hs1 : P.hs0;
    const float* bias = y1 ? P.bias1 : P.bias0;
    const float* pW   = y1 ? P.pW1 : P.pW0;
    const float* pb   = y1 ? P.pb1 : P.pb0;
    const float* fcW  = y1 ? P.fcW1 : P.fcW0;
    float* tab        = y1 ? P.tab1 : P.tab0;

    int lane = threadIdx.x & 63;
    int beg = rowptr[n], end = rowptr[n + 1];

    float den0 = 0.f, den1 = 0.f, den2 = 0.f, den3 = 0.f;
    float acc0 = 0.f, acc1 = 0.f;
    for (int i = beg; i < end; ++i) {
        float4 w4 = *reinterpret_cast<const float4*>(&wbuf[(size_t)i * 4]);
        den0 += w4.x; den1 += w4.y; den2 += w4.z; den3 += w4.w;
        int sn = cols[i];
        const float* hp = hs + (size_t)sn * 128;
        float wA = (lane < 32) ? w4.x : w4.y;
        float wB = (lane < 32) ? w4.z : w4.w;
        acc0 = fmaf(wA, hp[lane], acc0);
        acc1 = fmaf(wB, hp[64 + lane], acc1);
    }
    den0 += 1e-16f; den1 += 1e-16f; den2 += 1e-16f; den3 += 1e-16f;
    float d0 = lane < 32 ? den0 : den1;
    float d1 = lane < 32 ? den2 : den3;
    float v0 = fmaxf(acc0 / d0 + bias[lane], 0.f);
    float v1 = fmaxf(acc1 / d1 + bias[64 + lane], 0.f);
    float sum = v0 + __shfl_xor(v0, 32, 64) + v1 + __shfl_xor(v1, 32, 64);
    // every lane l now holds x[col = l&31] = 0.25*sum
    float xv = 0.25f * sum;

    float pp = xv * pW[lane & 31];
    pp += __shfl_xor(pp, 1, 64);
    pp += __shfl_xor(pp, 2, 64);
    pp += __shfl_xor(pp, 4, 64);
    pp += __shfl_xor(pp, 8, 64);
    pp += __shfl_xor(pp, 16, 64);
    float sc = __expf(pp + pb[0]);

    float accf = 0.f;
#pragma unroll
    for (int k = 0; k < 32; ++k) {
        float xk = __shfl(xv, k, 64);
        accf = fmaf(xk, fcW[k * 64 + lane], accf);
    }
    tab[(size_t)n * 64 + lane] = sc * accf;
}

// ---------------- link classifier: table gather + reduce ------------------
__global__ __launch_bounds__(256) void link_kernel(
    const float* __restrict__ Ad, const float* __restrict__ Bl,
    const int* __restrict__ eli,
    const float* __restrict__ fc1b, const float* __restrict__ fc2W,
    const float* __restrict__ fc2b,
    float* __restrict__ out, int EL)
{
    int wid = (blockIdx.x * 256 + threadIdx.x) >> 6;
    if (wid >= EL) return;
    int lane = threadIdx.x & 63;
    int e0 = eli[wid];
    int e1 = eli[EL + wid];
    float v = Ad[(size_t)e0 * 64 + lane] + Bl[(size_t)e1 * 64 + lane] + fc1b[lane];
    v = fmaxf(v, 0.f);
    float p = v * fc2W[lane];
#pragma unroll
    for (int off = 32; off >= 1; off >>= 1) p += __shfl_xor(p, off, 64);
    if (lane == 0) out[wid] = p + fc2b[0];
}

// ---------------------------------------------------------------------------
extern "C" void kernel_launch(void* const* d_in, const int* in_sizes, int n_in,
                              void* d_out, int out_size, void* d_ws, size_t ws_size,
                              hipStream_t stream)
{
    const int N  = in_sizes[6] / 128;
    const int Kd = in_sizes[2] / 128;   // 412
    const int Kl = in_sizes[4] / 128;   // 240
    const int KdP = (Kd + 31) & ~31;    // 416
    const int KlP = (Kl + 31) & ~31;    // 256
    const int E  = in_sizes[48] / 2;
    const int EL = in_sizes[49] / 2;

    const float* x_d    = (const float*)d_in[0];
    const float* x_l    = (const float*)d_in[1];
    const float* Wd_lin = (const float*)d_in[2];
    const float* bd_lin = (const float*)d_in[3];
    const float* Wl_lin = (const float*)d_in[4];
    const float* bl_lin = (const float*)d_in[5];
    const float* emb_d  = (const float*)d_in[6];
    const float* emb_l  = (const float*)d_in[7];

    const float *gWs[6], *gWd[6], *gas[6], *gad[6], *gb[6];
    for (int g = 0; g < 6; ++g) {
        gWs[g] = (const float*)d_in[8 + 5 * g + 0];
        gWd[g] = (const float*)d_in[8 + 5 * g + 1];
        gas[g] = (const float*)d_in[8 + 5 * g + 2];
        gad[g] = (const float*)d_in[8 + 5 * g + 3];
        gb[g]  = (const float*)d_in[8 + 5 * g + 4];
    }
    const float* pen_Wd = (const float*)d_in[38];
    const float* pen_bd = (const float*)d_in[39];
    const float* pen_Wl = (const float*)d_in[40];
    const float* pen_bl = (const float*)d_in[41];
    const float* fc1W   = (const float*)d_in[42];
    const float* fc1b   = (const float*)d_in[43];
    const float* fc2W   = (const float*)d_in[44];
    const float* fc2b   = (const float*)d_in[45];
    const int* node_id_d = (const int*)d_in[46];
    const int* node_id_l = (const int*)d_in[47];
    const int* ei  = (const int*)d_in[48];
    const int* eli = (const int*)d_in[49];
    const int* s_arr = ei;
    const int* t_arr = ei + E;

    // ---- workspace carve-up ----
    char* ws = (char*)d_ws;
    size_t off = 0;
    auto alloc = [&](size_t bytes) -> char* {
        char* p = ws + off;
        off = (off + bytes + 255) & ~(size_t)255;
        return p;
    };
    float* bufd0 = (float*)alloc((size_t)N * 128 * 4);
    float* bufd1 = (float*)alloc((size_t)N * 128 * 4);
    float* bufl0 = (float*)alloc((size_t)N * 128 * 4);
    float* bufl1 = (float*)alloc((size_t)N * 128 * 4);
    // region1 (N*2048 B): aggp0 | hs_d + hs_l
    char* region1 = alloc((size_t)N * 2048);
    u16* aggp0  = (u16*)region1;
    float* hs_d = (float*)region1;
    float* hs_l = (float*)(region1 + (size_t)N * 512);
    // weight planes
    u16* btWd = (u16*)alloc((size_t)2 * 128 * KdP * 2);
    u16* btWl = (u16*)alloc((size_t)2 * 128 * KlP * 2);
    u16* btWs[6];
    for (int g = 0; g < 6; ++g) {
        int J = (g < 4) ? 512 : 128;
        btWs[g] = (u16*)alloc((size_t)2 * J * 128 * 2);
    }
    float* es1  = (float*)alloc((size_t)N * 4 * 4);
    float* ed1  = (float*)alloc((size_t)N * 4 * 4);
    float* es2  = (float*)alloc((size_t)N * 4 * 4);
    float* ed2  = (float*)alloc((size_t)N * 4 * 4);
    float* Uall = (float*)alloc((size_t)6 * 1024 * 4);
    int* rpt_t = (int*)alloc((size_t)(N + 1) * 4);
    int* rpt_s = (int*)alloc((size_t)(N + 1) * 4);
    // zero-initialized block: deg_t | deg_s | cur_t | cur_s  (ONE memset)
    int* zero4 = (int*)alloc((size_t)4 * N * 4);
    int* deg_t = zero4;
    int* deg_s = zero4 + N;
    int* cur_t = zero4 + 2 * (size_t)N;
    int* cur_s = zero4 + 3 * (size_t)N;
    int* col_t = (int*)alloc((size_t)E * 4);
    int* col_s = (int*)alloc((size_t)E * 4);
    int* row_t = (int*)alloc((size_t)E * 4);
    int* row_s = (int*)alloc((size_t)E * 4);
    float* w_t = (float*)alloc((size_t)E * 4 * 4);
    float* w_s = (float*)alloc((size_t)E * 4 * 4);
    int* bs_t  = (int*)alloc(256 * 4);
    int* bs_s  = (int*)alloc(256 * 4);
    int* bo_t  = (int*)alloc(257 * 4);
    int* bo_s  = (int*)alloc(257 * 4);
    float* Ad  = (float*)alloc((size_t)N * 64 * 4);
    float* Bl  = (float*)alloc((size_t)N * 64 * 4);
    // optional second agg buffer for merged layer-1/2 pairs
    bool dual = (off + (size_t)N * 2048 + 256) <= ws_size;
    u16* aggp1 = dual ? (u16*)alloc((size_t)N * 2048) : aggp0;

    hipMemsetAsync(zero4, 0, (size_t)4 * N * 4, stream);

    dim3 blk(256);
    const int n64 = (N + 63) / 64;
    const int nEB = (E + 255) / 256;
    const int nAB = (N + 3) / 4;
    const int nT16 = (N * 16 + 255) / 256;

    // ---- fused: ALL weight splits || compute_U ----
    {
        SplitJobs SJ;
        const float* srcs[8] = {Wd_lin, Wl_lin, gWs[0], gWs[1], gWs[2], gWs[3], gWs[4], gWs[5]};
        u16* dsts[8] = {btWd, btWl, btWs[0], btWs[1], btWs[2], btWs[3], btWs[4], btWs[5]};
        int Ks[8]  = {Kd, Kl, 128, 128, 128, 128, 128, 128};
        int Kps[8] = {KdP, KlP, 128, 128, 128, 128, 128, 128};
        int Js[8]  = {128, 128, 512, 512, 512, 512, 128, 128};
        int acc = 0;
        for (int j = 0; j < 8; ++j) {
            SJ.src[j] = srcs[j]; SJ.dst[j] = dsts[j];
            SJ.K[j] = Ks[j]; SJ.Kp[j] = Kps[j]; SJ.J[j] = Js[j];
            SJ.offs[j] = acc;
            acc += Js[j] * Kps[j];
        }
        SJ.offs[8] = acc;
        UParams up;
        for (int g = 0; g < 6; ++g) {
            up.Ws[g] = gWs[g]; up.Wd[g] = gWd[g];
            up.as_[g] = gas[g]; up.ad_[g] = gad[g];
            up.C[g] = (g < 4) ? 128 : 32;
        }
        int gx = (acc + 255) / 256;
        if (gx < 1536) gx = 1536;
        k_split_U<<<dim3(gx, 2), blk, 0, stream>>>(SJ, up, Uall);
    }

    // ---- fused: input GEMM pair || degree count ----
    {
        GemmPairF P;
        P.A0 = x_d; P.B0 = btWd; P.bias0 = bd_lin; P.emb0 = emb_d;
        P.ids0 = node_id_d; P.C0 = bufd0; P.K0 = Kd; P.Kp0 = KdP;
        P.A1 = x_l; P.B1 = btWl; P.bias1 = bl_lin; P.emb1 = emb_l;
        P.ids1 = node_id_l; P.C1 = bufl0; P.K1 = Kl; P.Kp1 = KlP;
        int gx = (n64 > nEB) ? n64 : nEB;
        k_gemm_input_deg<<<dim3(gx, 3), blk, 0, stream>>>(
            P, N, n64, s_arr, t_arr, deg_t, deg_s, E);
    }

    // ---- CSR scans ----
    {
        int nb = (N + 255) / 256;
        scan_partial<<<dim3(nb, 2), blk, 0, stream>>>(deg_t, deg_s, rpt_t, rpt_s, bs_t, bs_s, N);
        scan_bsums<<<dim3(1, 2), blk, 0, stream>>>(bs_t, bs_s, bo_t, bo_s, nb);
        scan_add<<<dim3(nb, 2), blk, 0, stream>>>(rpt_t, rpt_s, bo_t, bo_s, N, nb);
    }

    float* xd_cur = bufd0; float* xl_cur = bufl0;
    float* xd_nxt = bufd1; float* xl_nxt = bufl1;

    // ---- layer 1: fused fill || es_ed2 ----
    {
        int gx = (nEB > nT16) ? nEB : nT16;
        k_fill_esed<<<dim3(gx, 2), blk, 0, stream>>>(
            s_arr, t_arr, rpt_t, rpt_s, cur_t, cur_s,
            col_t, col_s, row_t, row_s, E,
            xd_cur, xl_cur, Uall + 0 * 1024, Uall + 1 * 1024,
            es1, ed1, es2, ed2, N);
    }

    for (int L = 0; L < 2; ++L) {
        const int gd = 2 * L, gl = 2 * L + 1;

        if (L > 0) {
            es_ed2_kernel<<<dim3(nT16), blk, 0, stream>>>(
                xd_cur, xl_cur, Uall + gd * 1024, Uall + gl * 1024,
                es1, ed1, es2, ed2, N);
        }
        edge_w_kernel<<<dim3(nEB, 2), blk, 0, stream>>>(
            col_t, row_t, col_s, row_s, es1, ed1, es2, ed2, w_t, w_s, E);

        if (dual) {
            AggXPair AP;
            AP.rpt0 = rpt_t; AP.col0 = col_t; AP.w0 = w_t; AP.x0 = xd_cur; AP.out0 = aggp0;
            AP.rpt1 = rpt_s; AP.col1 = col_s; AP.w1 = w_s; AP.x1 = xl_cur; AP.out1 = aggp1;
            agg_x2<<<dim3(nAB, 2), blk, 0, stream>>>(AP, N);

            HeadsPair HP;
            HP.A0 = aggp0; HP.B0 = btWs[gd]; HP.bias0 = gb[gd]; HP.C0 = xl_nxt;
            HP.A1 = aggp1; HP.B1 = btWs[gl]; HP.bias1 = gb[gl]; HP.C1 = xd_nxt;
            gemm_heads2<<<dim3(n64, 2), blk, 0, stream>>>(HP, N);
        } else {
            AggXPair AP;
            AP.rpt0 = rpt_t; AP.col0 = col_t; AP.w0 = w_t; AP.x0 = xd_cur; AP.out0 = aggp0;
            AP.rpt1 = AP.rpt0; AP.col1 = AP.col0; AP.w1 = AP.w0; AP.x1 = AP.x0; AP.out1 = AP.out0;
            agg_x2<<<dim3(nAB, 1), blk, 0, stream>>>(AP, N);
            HeadsPair HP;
            HP.A0 = aggp0; HP.B0 = btWs[gd]; HP.bias0 = gb[gd]; HP.C0 = xl_nxt;
            HP.A1 = HP.A0; HP.B1 = HP.B0; HP.bias1 = HP.bias0; HP.C1 = HP.C0;
            gemm_heads2<<<dim3(n64, 1), blk, 0, stream>>>(HP, N);

            AP.rpt0 = rpt_s; AP.col0 = col_s; AP.w0 = w_s; AP.x0 = xl_cur; AP.out0 = aggp0;
            AP.rpt1 = AP.rpt0; AP.col1 = AP.col0; AP.w1 = AP.w0; AP.x1 = AP.x0; AP.out1 = AP.out0;
            agg_x2<<<dim3(nAB, 1), blk, 0, stream>>>(AP, N);
            HP.A0 = aggp0; HP.B0 = btWs[gl]; HP.bias0 = gb[gl]; HP.C0 = xd_nxt;
            HP.A1 = HP.A0; HP.B1 = HP.B0; HP.bias1 = HP.bias0; HP.C1 = HP.C0;
            gemm_heads2<<<dim3(n64, 1), blk, 0, stream>>>(HP, N);
        }

        float* tmp;
        tmp = xd_cur; xd_cur = xd_nxt; xd_nxt = tmp;
        tmp = xl_cur; xl_cur = xl_nxt; xl_nxt = tmp;
    }

    // ---- layer 3: fused GEMM pair || es_ed2, then edge_w, fused agg+fc1 ----
    {
        const int gd = 4, gl = 5;

        GemmPairF P;
        P.A0 = xd_cur; P.B0 = btWs[gd]; P.bias0 = nullptr; P.emb0 = nullptr;
        P.ids0 = nullptr; P.C0 = hs_d; P.K0 = 128; P.Kp0 = 128;
        P.A1 = xl_cur; P.B1 = btWs[gl]; P.bias1 = nullptr; P.emb1 = nullptr;
        P.ids1 = nullptr; P.C1 = hs_l; P.K1 = 128; P.Kp1 = 128;
        int gx = (n64 > nT16) ? n64 : nT16;
        k_gemm_l3_esed<<<dim3(gx, 3), blk, 0, stream>>>(
            P, N, n64, xd_cur, xl_cur, Uall + gd * 1024, Uall + gl * 1024,
            es1, ed1, es2, ed2);

        edge_w_kernel<<<dim3(nEB, 2), blk, 0, stream>>>(
            col_t, row_t, col_s, row_s, es1, ed1, es2, ed2, w_t, w_s, E);

        Agg128Pair AP;
        AP.rpt0 = rpt_t; AP.col0 = col_t; AP.w0 = w_t;
        AP.hs0 = hs_d; AP.bias0 = gb[gd];
        AP.pW0 = pen_Wl; AP.pb0 = pen_bl; AP.fcW0 = fc1W + 32 * 64; AP.tab0 = Bl;
        AP.rpt1 = rpt_s; AP.col1 = col_s; AP.w1 = w_s;
        AP.hs1 = hs_l; AP.bias1 = gb[gl];
        AP.pW1 = pen_Wd; AP.pb1 = pen_bd; AP.fcW1 = fc1W; AP.tab1 = Ad;
        gat_agg128_fc1<<<dim3(nAB, 2), blk, 0, stream>>>(AP, N);
    }

    // link classifier on supervision edges
    link_kernel<<<dim3((EL + 3) / 4), blk, 0, stream>>>(
        Ad, Bl, eli, fc1b, fc2W, fc2b, (float*)d_out, EL);
}